// Round 5
// baseline (785.179 us; speedup 1.0000x reference)
//
#include <hip/hip_runtime.h>
#include <math.h>

#define N_TOK   262144
#define DIMV    128
#define KCODE   1024
#define LEV     3
#define BLOCK   256
#define NTILES  64          // 16-code tiles per level
#define EPS     0.08f       // fp16 2-product distance error band (~40 sigma)

// ws byte layout: [0,8)=loss double; ee64[3072] doubles @64; ee32b[3072] floats @24640;
// B-frag buffer (fp16, MFMA lane layout) @36928, size 3*64*4*1024 = 786432 B.
#define WS_EE64_B  64
#define WS_EE32_B  24640
#define WS_FRAG_B  36928

typedef _Float16 f16x8 __attribute__((ext_vector_type(8)));
typedef float f32x4 __attribute__((ext_vector_type(4)));

// prep: per-code ||e||^2 (fp64) + fp16 conversion into the exact MFMA B-frag layout:
// frag chunk for (level l, tile t, kstep st): 1024B, lane*16B; lane holds
// code = t*16 + (lane&15), dims st*32 + (lane>>4)*8 + j.
__global__ void rvq_prep(const float* __restrict__ cb, double* __restrict__ ws) {
    int c = blockIdx.x * blockDim.x + threadIdx.x;
    if (c == 0) ws[0] = 0.0;
    if (c >= LEV * KCODE) return;
    const float* e = cb + (size_t)c * DIMV;
    const int lvl = c >> 10, ci = c & 1023, t4 = ci >> 4, n = ci & 15;
    unsigned char* fb = (unsigned char*)ws + WS_FRAG_B + (((size_t)(lvl * 64 + t4)) << 12);
    double s = 0.0;
    #pragma unroll
    for (int st = 0; st < 4; ++st)
        #pragma unroll
        for (int kq = 0; kq < 4; ++kq) {
            float4 a = *(const float4*)(e + st*32 + kq*8);
            float4 b = *(const float4*)(e + st*32 + kq*8 + 4);
            f16x8 h;
            h[0]=(_Float16)a.x; h[1]=(_Float16)a.y; h[2]=(_Float16)a.z; h[3]=(_Float16)a.w;
            h[4]=(_Float16)b.x; h[5]=(_Float16)b.y; h[6]=(_Float16)b.z; h[7]=(_Float16)b.w;
            s = fma((double)a.x,(double)a.x,s); s = fma((double)a.y,(double)a.y,s);
            s = fma((double)a.z,(double)a.z,s); s = fma((double)a.w,(double)a.w,s);
            s = fma((double)b.x,(double)b.x,s); s = fma((double)b.y,(double)b.y,s);
            s = fma((double)b.z,(double)b.z,s); s = fma((double)b.w,(double)b.w,s);
            *(f16x8*)(fb + st*1024 + ((kq*16 + n) << 4)) = h;
        }
    ((double*)((unsigned char*)ws + WS_EE64_B))[c] = s;
    ((float*)((unsigned char*)ws + WS_EE32_B))[c] = (float)(s + 8192.0);
}

__device__ inline unsigned sel4(const unsigned v[4], int j) {
    unsigned a = (j & 1) ? v[1] : v[0];
    unsigned b = (j & 1) ? v[3] : v[2];
    return (j & 2) ? b : a;
}

// top-2 update: m2' = median(m1, m2, k) given invariant m1 <= m2 (single VALU op)
__device__ inline unsigned umed3(unsigned a, unsigned b, unsigned c) {
    unsigned d;
    asm("v_med3_u32 %0, %1, %2, %3" : "=v"(d) : "v"(a), "v"(b), "v"(c));
    return d;
}

__global__ __launch_bounds__(BLOCK, 2) void rvq_main(const float* __restrict__ ze,
                                                     const float* __restrict__ cb,
                                                     float* __restrict__ out,
                                                     double* __restrict__ ws) {
    __shared__ double ssum[4];

    const double* __restrict__ ee64g = (const double*)((const unsigned char*)ws + WS_EE64_B);
    const float*  __restrict__ eebg  = (const float*)((const unsigned char*)ws + WS_EE32_B);
    const unsigned char* __restrict__ fbase = (const unsigned char*)ws + WS_FRAG_B;

    const int tid  = threadIdx.x;
    const int lane = tid & 63;
    const int wid  = tid >> 6;
    const int q    = lane >> 4;   // quad: owns dims st*32 + q*8 + j
    const int col  = lane & 15;   // B-operand col (code) / A-operand row (token)
    const long tokbase = (long)blockIdx.x * 128 + wid * 32;

    float r[2][4][8];             // residual, fp32, reference-exact op chain
    f16x8 Ah[2][4], Al[2][4];     // A-frags: hi/lo fp16 split of (-2*residual)

    #pragma unroll
    for (int mt = 0; mt < 2; ++mt) {
        const float4* zp = (const float4*)(ze + (size_t)(tokbase + mt*16 + col) * DIMV);
        #pragma unroll
        for (int st = 0; st < 4; ++st) {
            float4 a = zp[st*8 + q*2], b = zp[st*8 + q*2 + 1];
            r[mt][st][0]=a.x; r[mt][st][1]=a.y; r[mt][st][2]=a.z; r[mt][st][3]=a.w;
            r[mt][st][4]=b.x; r[mt][st][5]=b.y; r[mt][st][6]=b.z; r[mt][st][7]=b.w;
        }
    }
    // A-frags scaled by -2 (exact pow2 scale): MFMA accumulates eeq - 2*dot = d + 8192
    #pragma unroll
    for (int mt = 0; mt < 2; ++mt)
        #pragma unroll
        for (int st = 0; st < 4; ++st) {
            f16x8 h, lo;
            #pragma unroll
            for (int j = 0; j < 8; ++j) {
                float y = -2.0f * r[mt][st][j];
                _Float16 hh = (_Float16)y;
                h[j] = hh;
                lo[j] = (_Float16)(y - (float)hh);
            }
            Ah[mt][st] = h; Al[mt][st] = lo;
        }

    double loss = 0.0;
    float* out_idx = out + (size_t)N_TOK * DIMV + 2;

// 4 independent accumulator chains (dep distance 4): c0a/c0b for mt=0 (ksteps 01 / 23),
// c1a/c1b for mt=1. Reassociation shifts the approx distance by ~1 ulp << EPS.
#define TILE_COMPUTE(B, EEQ, T)                                                      \
    do {                                                                             \
        f32x4 c0a = {(EEQ),(EEQ),(EEQ),(EEQ)};                                       \
        f32x4 c1a = {(EEQ),(EEQ),(EEQ),(EEQ)};                                       \
        f32x4 c0b = {0.f,0.f,0.f,0.f};                                               \
        f32x4 c1b = {0.f,0.f,0.f,0.f};                                               \
        c0a = __builtin_amdgcn_mfma_f32_16x16x32_f16(Ah[0][0], (B)[0], c0a, 0,0,0);  \
        c1a = __builtin_amdgcn_mfma_f32_16x16x32_f16(Ah[1][0], (B)[0], c1a, 0,0,0);  \
        c0b = __builtin_amdgcn_mfma_f32_16x16x32_f16(Ah[0][2], (B)[2], c0b, 0,0,0);  \
        c1b = __builtin_amdgcn_mfma_f32_16x16x32_f16(Ah[1][2], (B)[2], c1b, 0,0,0);  \
        c0a = __builtin_amdgcn_mfma_f32_16x16x32_f16(Al[0][0], (B)[0], c0a, 0,0,0);  \
        c1a = __builtin_amdgcn_mfma_f32_16x16x32_f16(Al[1][0], (B)[0], c1a, 0,0,0);  \
        c0b = __builtin_amdgcn_mfma_f32_16x16x32_f16(Al[0][2], (B)[2], c0b, 0,0,0);  \
        c1b = __builtin_amdgcn_mfma_f32_16x16x32_f16(Al[1][2], (B)[2], c1b, 0,0,0);  \
        c0a = __builtin_amdgcn_mfma_f32_16x16x32_f16(Ah[0][1], (B)[1], c0a, 0,0,0);  \
        c1a = __builtin_amdgcn_mfma_f32_16x16x32_f16(Ah[1][1], (B)[1], c1a, 0,0,0);  \
        c0b = __builtin_amdgcn_mfma_f32_16x16x32_f16(Ah[0][3], (B)[3], c0b, 0,0,0);  \
        c1b = __builtin_amdgcn_mfma_f32_16x16x32_f16(Ah[1][3], (B)[3], c1b, 0,0,0);  \
        c0a = __builtin_amdgcn_mfma_f32_16x16x32_f16(Al[0][1], (B)[1], c0a, 0,0,0);  \
        c1a = __builtin_amdgcn_mfma_f32_16x16x32_f16(Al[1][1], (B)[1], c1a, 0,0,0);  \
        c0b = __builtin_amdgcn_mfma_f32_16x16x32_f16(Al[0][3], (B)[3], c0b, 0,0,0);  \
        c1b = __builtin_amdgcn_mfma_f32_16x16x32_f16(Al[1][3], (B)[3], c1b, 0,0,0);  \
        f32x4 c0 = c0a + c0b, c1v = c1a + c1b;                                       \
        _Pragma("unroll")                                                            \
        for (int i = 0; i < 4; ++i) {                                                \
            unsigned k0 = (__float_as_uint(c0[i]) << 6) | (unsigned)(T);             \
            m2[0][i] = umed3(m1[0][i], m2[0][i], k0);                                \
            m1[0][i] = min(m1[0][i], k0);                                            \
            unsigned k1_ = (__float_as_uint(c1v[i]) << 6) | (unsigned)(T);           \
            m2[1][i] = umed3(m1[1][i], m2[1][i], k1_);                               \
            m1[1][i] = min(m1[1][i], k1_);                                           \
        }                                                                            \
    } while (0)

    for (int l = 0; l < LEV; ++l) {
        const unsigned char* bp = fbase + ((size_t)l << 18) + (lane << 4);
        const float* eep = eebg + l * KCODE + col;

        f16x8 Ba[4], Bb[4];
        #pragma unroll
        for (int st = 0; st < 4; ++st) Ba[st] = *(const f16x8*)(bp + st*1024);
        float eeq_a = eep[0], eeq_b;

        unsigned m1[2][4], m2[2][4];
        #pragma unroll
        for (int mt = 0; mt < 2; ++mt)
            #pragma unroll
            for (int i = 0; i < 4; ++i) { m1[mt][i] = 0xFFFFFFFFu; m2[mt][i] = 0xFFFFFFFFu; }

        for (int t = 0; t < NTILES; t += 2) {
            {   // prefetch t+1 (always valid: t <= 62)
                const unsigned char* np = bp + 4096;
                #pragma unroll
                for (int st = 0; st < 4; ++st) Bb[st] = *(const f16x8*)(np + st*1024);
                eeq_b = eep[16];
            }
            TILE_COMPUTE(Ba, eeq_a, t);
            {   // prefetch t+2 (clamped at the tail; values unused when t==62)
                const unsigned char* np = (t + 2 < NTILES) ? bp + 8192 : bp;
                const float* ep2 = (t + 2 < NTILES) ? eep + 32 : eep;
                #pragma unroll
                for (int st = 0; st < 4; ++st) Ba[st] = *(const f16x8*)(np + st*1024);
                eeq_a = ep2[0];
            }
            TILE_COMPUTE(Bb, eeq_b, t + 1);
            bp += 8192; eep += 32;
        }

        // ---- phase 2: cross-lane top-2 reduce (with lane-col meta), select, rescore, update ----
        unsigned k1[2][4], k2[2][4], q1[2][4], q2[2][4];
        #pragma unroll
        for (int mt = 0; mt < 2; ++mt)
            #pragma unroll
            for (int i = 0; i < 4; ++i) {
                k1[mt][i] = m1[mt][i]; k2[mt][i] = m2[mt][i];
                q1[mt][i] = (unsigned)col; q2[mt][i] = (unsigned)col;
            }
        #pragma unroll
        for (int d = 1; d <= 8; d <<= 1) {
            #pragma unroll
            for (int mt = 0; mt < 2; ++mt)
                #pragma unroll
                for (int i = 0; i < 4; ++i) {
                    unsigned ok1 = __shfl_xor(k1[mt][i], d), oq1 = __shfl_xor(q1[mt][i], d);
                    unsigned ok2 = __shfl_xor(k2[mt][i], d), oq2 = __shfl_xor(q2[mt][i], d);
                    bool sw = (ok1 < k1[mt][i]) || (ok1 == k1[mt][i] && oq1 < q1[mt][i]);
                    unsigned n1 = sw ? ok1 : k1[mt][i], nq1 = sw ? oq1 : q1[mt][i];
                    unsigned hk = sw ? k1[mt][i] : ok1, hq = sw ? q1[mt][i] : oq1;
                    bool s2 = (ok2 < k2[mt][i]) || (ok2 == k2[mt][i] && oq2 < q2[mt][i]);
                    unsigned p2 = s2 ? ok2 : k2[mt][i], pq = s2 ? oq2 : q2[mt][i];
                    bool s3 = (p2 < hk) || (p2 == hk && pq < hq);
                    k1[mt][i] = n1;              q1[mt][i] = nq1;
                    k2[mt][i] = s3 ? p2 : hk;    q2[mt][i] = s3 ? pq : hq;
                }
        }

        int jsel = (lane >> 2) & 3;
        int S = ((col >> 2) << 4) | ((col & 3) << 2);   // source lane holding token col's keys

        #pragma unroll
        for (int mt = 0; mt < 2; ++mt) {
            unsigned sk1 = sel4(k1[mt], jsel), sq1 = sel4(q1[mt], jsel);
            unsigned sk2 = sel4(k2[mt], jsel), sq2 = sel4(q2[mt], jsel);
            unsigned bk1 = (unsigned)__shfl((int)sk1, S);
            unsigned bq1 = (unsigned)__shfl((int)sq1, S);
            unsigned bk2 = (unsigned)__shfl((int)sk2, S);
            unsigned bq2 = (unsigned)__shfl((int)sq2, S);
            int c1c = (int)(((bk1 & 63u) << 4) | bq1);
            int c2c = (int)(((bk2 & 63u) << 4) | bq2);
            float d1 = __uint_as_float((bk1 >> 6) | 0x44000000u) - 8192.0f;
            float d2 = __uint_as_float((bk2 >> 6) | 0x44000000u) - 8192.0f;
            int bc = c1c;
            if (d2 - d1 < EPS) {   // ambiguous: exact fp64 rescore of both (uniform per token group)
                double s1 = 0.0, s2d = 0.0;
                const float4* e1 = (const float4*)(cb + ((size_t)l*KCODE + c1c)*DIMV);
                const float4* e2 = (const float4*)(cb + ((size_t)l*KCODE + c2c)*DIMV);
                #pragma unroll
                for (int st = 0; st < 4; ++st) {
                    float4 a = e1[st*8 + q*2], b = e1[st*8 + q*2 + 1];
                    s1 = fma((double)a.x,(double)r[mt][st][0],s1); s1 = fma((double)a.y,(double)r[mt][st][1],s1);
                    s1 = fma((double)a.z,(double)r[mt][st][2],s1); s1 = fma((double)a.w,(double)r[mt][st][3],s1);
                    s1 = fma((double)b.x,(double)r[mt][st][4],s1); s1 = fma((double)b.y,(double)r[mt][st][5],s1);
                    s1 = fma((double)b.z,(double)r[mt][st][6],s1); s1 = fma((double)b.w,(double)r[mt][st][7],s1);
                    float4 a2 = e2[st*8 + q*2], b2 = e2[st*8 + q*2 + 1];
                    s2d = fma((double)a2.x,(double)r[mt][st][0],s2d); s2d = fma((double)a2.y,(double)r[mt][st][1],s2d);
                    s2d = fma((double)a2.z,(double)r[mt][st][2],s2d); s2d = fma((double)a2.w,(double)r[mt][st][3],s2d);
                    s2d = fma((double)b2.x,(double)r[mt][st][4],s2d); s2d = fma((double)b2.y,(double)r[mt][st][5],s2d);
                    s2d = fma((double)b2.z,(double)r[mt][st][6],s2d); s2d = fma((double)b2.w,(double)r[mt][st][7],s2d);
                }
                s1  += __shfl_xor(s1, 16);  s1  += __shfl_xor(s1, 32);
                s2d += __shfl_xor(s2d, 16); s2d += __shfl_xor(s2d, 32);
                double dd1 = ee64g[l*KCODE + c1c] - 2.0*s1;
                double dd2 = ee64g[l*KCODE + c2c] - 2.0*s2d;
                if (dd2 < dd1 || (dd2 == dd1 && c2c < c1c)) bc = c2c;
            }
            // residual update: reference-exact fp32 op chain
            const float4* eb = (const float4*)(cb + ((size_t)l*KCODE + bc)*DIMV);
            #pragma unroll
            for (int st = 0; st < 4; ++st) {
                float4 a = eb[st*8 + q*2], b = eb[st*8 + q*2 + 1];
                float qv[8] = {a.x,a.y,a.z,a.w,b.x,b.y,b.z,b.w};
                #pragma unroll
                for (int j = 0; j < 8; ++j) {
                    float rv = r[mt][st][j];
                    float t1 = qv[j] - rv;              // z_q - residual
                    loss += (double)t1 * (double)t1;
                    float zqst = rv + t1;               // straight-through
                    r[mt][st][j] = rv - zqst;
                }
            }
            if (l < LEV - 1) {   // rebuild A-frags (scaled by -2) for next level
                #pragma unroll
                for (int st = 0; st < 4; ++st) {
                    f16x8 h, lo;
                    #pragma unroll
                    for (int j = 0; j < 8; ++j) {
                        float y = -2.0f * r[mt][st][j];
                        _Float16 hh = (_Float16)y;
                        h[j] = hh;
                        lo[j] = (_Float16)(y - (float)hh);
                    }
                    Ah[mt][st] = h; Al[mt][st] = lo;
                }
            } else {             // final output: z_q_total = z_e - residual_final
                const float4* zp = (const float4*)(ze + (size_t)(tokbase + mt*16 + col)*DIMV);
                float4* op = (float4*)(out + (size_t)(tokbase + mt*16 + col)*DIMV);
                #pragma unroll
                for (int st = 0; st < 4; ++st) {
                    float4 za = zp[st*8 + q*2], zb = zp[st*8 + q*2 + 1];
                    float4 oa, ob;
                    oa.x = za.x - r[mt][st][0]; oa.y = za.y - r[mt][st][1];
                    oa.z = za.z - r[mt][st][2]; oa.w = za.w - r[mt][st][3];
                    ob.x = zb.x - r[mt][st][4]; ob.y = zb.y - r[mt][st][5];
                    ob.z = zb.z - r[mt][st][6]; ob.w = zb.w - r[mt][st][7];
                    op[st*8 + q*2] = oa; op[st*8 + q*2 + 1] = ob;
                }
            }
            if (q == 0) out_idx[(size_t)(tokbase + mt*16 + col)*3 + l] = (float)bc;
        }
    }

    #pragma unroll
    for (int d = 1; d <= 32; d <<= 1) loss += __shfl_xor(loss, d);
    if ((tid & 63) == 0) ssum[wid] = loss;
    __syncthreads();
    if (tid == 0) atomicAdd(ws, ssum[0] + ssum[1] + ssum[2] + ssum[3]);
}

__global__ void rvq_fin(const double* __restrict__ ws, float* __restrict__ out) {
    double vq = ws[0] / ((double)N_TOK * (double)DIMV * (double)LEV);
    out[(size_t)N_TOK * DIMV + 0] = (float)vq;
    out[(size_t)N_TOK * DIMV + 1] = (float)(0.25 * vq);
}

extern "C" void kernel_launch(void* const* d_in, const int* in_sizes, int n_in,
                              void* d_out, int out_size, void* d_ws, size_t ws_size,
                              hipStream_t stream) {
    const float* ze = (const float*)d_in[0];
    const float* cb = (const float*)d_in[1];
    float* out = (float*)d_out;
    double* ws = (double*)d_ws;

    rvq_prep<<<(LEV * KCODE + 255) / 256, 256, 0, stream>>>(cb, ws);
    rvq_main<<<N_TOK / 128, BLOCK, 0, stream>>>(ze, cb, out, ws);
    rvq_fin<<<1, 1, 0, stream>>>(ws, out);
}

// Round 6
// 717.916 us; speedup vs baseline: 1.0937x; 1.0937x over previous
//
#include <hip/hip_runtime.h>
#include <math.h>

#define N_TOK   262144
#define DIMV    128
#define KCODE   1024
#define LEV     3
#define BLOCK   256
#define NTILES  64          // 16-code tiles per level
#define RDEPTH  4           // per-wave LDS ring depth (tiles)
#define EPS     0.08f       // fp16 2-product distance error band (~40 sigma)

// ws byte layout: [0,8)=loss double; ee64[3072] doubles @64; ee32b[3072] floats @24640;
// B-frag buffer (fp16, MFMA lane layout) @36928, size 3*64*4*1024 = 786432 B.
#define WS_EE64_B  64
#define WS_EE32_B  24640
#define WS_FRAG_B  36928

typedef _Float16 f16x8 __attribute__((ext_vector_type(8)));
typedef float f32x4 __attribute__((ext_vector_type(4)));

// prep: per-code ||e||^2 (fp64) + fp16 conversion into the exact MFMA B-frag layout:
// frag chunk for (level l, tile t, kstep st): 1024B, lane*16B; lane holds
// code = t*16 + (lane&15), dims st*32 + (lane>>4)*8 + j.
__global__ void rvq_prep(const float* __restrict__ cb, double* __restrict__ ws) {
    int c = blockIdx.x * blockDim.x + threadIdx.x;
    if (c == 0) ws[0] = 0.0;
    if (c >= LEV * KCODE) return;
    const float* e = cb + (size_t)c * DIMV;
    const int lvl = c >> 10, ci = c & 1023, t4 = ci >> 4, n = ci & 15;
    unsigned char* fb = (unsigned char*)ws + WS_FRAG_B + (((size_t)(lvl * 64 + t4)) << 12);
    double s = 0.0;
    #pragma unroll
    for (int st = 0; st < 4; ++st)
        #pragma unroll
        for (int kq = 0; kq < 4; ++kq) {
            float4 a = *(const float4*)(e + st*32 + kq*8);
            float4 b = *(const float4*)(e + st*32 + kq*8 + 4);
            f16x8 h;
            h[0]=(_Float16)a.x; h[1]=(_Float16)a.y; h[2]=(_Float16)a.z; h[3]=(_Float16)a.w;
            h[4]=(_Float16)b.x; h[5]=(_Float16)b.y; h[6]=(_Float16)b.z; h[7]=(_Float16)b.w;
            s = fma((double)a.x,(double)a.x,s); s = fma((double)a.y,(double)a.y,s);
            s = fma((double)a.z,(double)a.z,s); s = fma((double)a.w,(double)a.w,s);
            s = fma((double)b.x,(double)b.x,s); s = fma((double)b.y,(double)b.y,s);
            s = fma((double)b.z,(double)b.z,s); s = fma((double)b.w,(double)b.w,s);
            *(f16x8*)(fb + st*1024 + ((kq*16 + n) << 4)) = h;
        }
    ((double*)((unsigned char*)ws + WS_EE64_B))[c] = s;
    ((float*)((unsigned char*)ws + WS_EE32_B))[c] = (float)(s + 8192.0);
}

__device__ inline unsigned sel4(const unsigned v[4], int j) {
    unsigned a = (j & 1) ? v[1] : v[0];
    unsigned b = (j & 1) ? v[3] : v[2];
    return (j & 2) ? b : a;
}

// top-2 update: m2' = median(m1, m2, k) given invariant m1 <= m2 (single VALU op)
__device__ inline unsigned umed3(unsigned a, unsigned b, unsigned c) {
    unsigned d;
    asm("v_med3_u32 %0, %1, %2, %3" : "=v"(d) : "v"(a), "v"(b), "v"(c));
    return d;
}

// async DMA of one 4KB frag tile (this wave's private copy): 4 x global_load_lds width-16.
// g includes this lane's chunk offset (lane*16); LDS dest is wave-uniform, HW adds lane*16.
__device__ inline void dma_tile(const unsigned char* g, unsigned char* l) {
    #pragma unroll
    for (int st = 0; st < 4; ++st)
        __builtin_amdgcn_global_load_lds(
            (const __attribute__((address_space(1))) void*)(g + st*1024),
            (__attribute__((address_space(3))) void*)(l + st*1024),
            16, 0, 0);
}

#define WAITV(N) asm volatile("s_waitcnt vmcnt(" #N ")" ::: "memory")

__global__ __launch_bounds__(BLOCK, 2) void rvq_main(const float* __restrict__ ze,
                                                     const float* __restrict__ cb,
                                                     float* __restrict__ out,
                                                     double* __restrict__ ws) {
    __shared__ __align__(16) unsigned char Bring[4 * RDEPTH * 4096];  // per-wave private rings
    __shared__ __align__(16) float eeS[KCODE];
    __shared__ double ssum[4];

    const double* __restrict__ ee64g = (const double*)((const unsigned char*)ws + WS_EE64_B);
    const float*  __restrict__ eebg  = (const float*)((const unsigned char*)ws + WS_EE32_B);
    const unsigned char* __restrict__ fbase = (const unsigned char*)ws + WS_FRAG_B;

    const int tid  = threadIdx.x;
    const int lane = tid & 63;
    const int wid  = tid >> 6;
    const int q    = lane >> 4;   // quad: owns dims st*32 + q*8 + j
    const int col  = lane & 15;   // B-operand col (code) / A-operand row (token)
    const long tokbase = (long)blockIdx.x * 128 + wid * 32;

    unsigned char* ring = Bring + (size_t)wid * (RDEPTH * 4096);

    float r[2][4][8];             // residual, fp32, reference-exact op chain
    f16x8 Ah[2][4], Al[2][4];     // A-frags: hi/lo fp16 split of (-2*residual)

    #pragma unroll
    for (int mt = 0; mt < 2; ++mt) {
        const float4* zp = (const float4*)(ze + (size_t)(tokbase + mt*16 + col) * DIMV);
        #pragma unroll
        for (int st = 0; st < 4; ++st) {
            float4 a = zp[st*8 + q*2], b = zp[st*8 + q*2 + 1];
            r[mt][st][0]=a.x; r[mt][st][1]=a.y; r[mt][st][2]=a.z; r[mt][st][3]=a.w;
            r[mt][st][4]=b.x; r[mt][st][5]=b.y; r[mt][st][6]=b.z; r[mt][st][7]=b.w;
        }
    }
    // A-frags scaled by -2 (exact pow2 scale): MFMA accumulates eeq - 2*dot = d + 8192
    #pragma unroll
    for (int mt = 0; mt < 2; ++mt)
        #pragma unroll
        for (int st = 0; st < 4; ++st) {
            f16x8 h, lo;
            #pragma unroll
            for (int j = 0; j < 8; ++j) {
                float y = -2.0f * r[mt][st][j];
                _Float16 hh = (_Float16)y;
                h[j] = hh;
                lo[j] = (_Float16)(y - (float)hh);
            }
            Ah[mt][st] = h; Al[mt][st] = lo;
        }

    double loss = 0.0;
    float* out_idx = out + (size_t)N_TOK * DIMV + 2;

// 2 accumulator chains, k-major, dependency distance 2 (R5's 4-chain split was null).
#define TILE_COMPUTE(B, EEQ, T)                                                      \
    do {                                                                             \
        f32x4 c0  = {(EEQ),(EEQ),(EEQ),(EEQ)};                                       \
        f32x4 c1v = {(EEQ),(EEQ),(EEQ),(EEQ)};                                       \
        c0  = __builtin_amdgcn_mfma_f32_16x16x32_f16(Ah[0][0], (B)[0], c0,  0,0,0);  \
        c1v = __builtin_amdgcn_mfma_f32_16x16x32_f16(Ah[1][0], (B)[0], c1v, 0,0,0);  \
        c0  = __builtin_amdgcn_mfma_f32_16x16x32_f16(Al[0][0], (B)[0], c0,  0,0,0);  \
        c1v = __builtin_amdgcn_mfma_f32_16x16x32_f16(Al[1][0], (B)[0], c1v, 0,0,0);  \
        c0  = __builtin_amdgcn_mfma_f32_16x16x32_f16(Ah[0][1], (B)[1], c0,  0,0,0);  \
        c1v = __builtin_amdgcn_mfma_f32_16x16x32_f16(Ah[1][1], (B)[1], c1v, 0,0,0);  \
        c0  = __builtin_amdgcn_mfma_f32_16x16x32_f16(Al[0][1], (B)[1], c0,  0,0,0);  \
        c1v = __builtin_amdgcn_mfma_f32_16x16x32_f16(Al[1][1], (B)[1], c1v, 0,0,0);  \
        c0  = __builtin_amdgcn_mfma_f32_16x16x32_f16(Ah[0][2], (B)[2], c0,  0,0,0);  \
        c1v = __builtin_amdgcn_mfma_f32_16x16x32_f16(Ah[1][2], (B)[2], c1v, 0,0,0);  \
        c0  = __builtin_amdgcn_mfma_f32_16x16x32_f16(Al[0][2], (B)[2], c0,  0,0,0);  \
        c1v = __builtin_amdgcn_mfma_f32_16x16x32_f16(Al[1][2], (B)[2], c1v, 0,0,0);  \
        c0  = __builtin_amdgcn_mfma_f32_16x16x32_f16(Ah[0][3], (B)[3], c0,  0,0,0);  \
        c1v = __builtin_amdgcn_mfma_f32_16x16x32_f16(Ah[1][3], (B)[3], c1v, 0,0,0);  \
        c0  = __builtin_amdgcn_mfma_f32_16x16x32_f16(Al[0][3], (B)[3], c0,  0,0,0);  \
        c1v = __builtin_amdgcn_mfma_f32_16x16x32_f16(Al[1][3], (B)[3], c1v, 0,0,0);  \
        _Pragma("unroll")                                                            \
        for (int i = 0; i < 4; ++i) {                                                \
            unsigned k0 = (__float_as_uint(c0[i]) << 6) | (unsigned)(T);             \
            m2[0][i] = umed3(m1[0][i], m2[0][i], k0);                                \
            m1[0][i] = min(m1[0][i], k0);                                            \
            unsigned k1_ = (__float_as_uint(c1v[i]) << 6) | (unsigned)(T);           \
            m2[1][i] = umed3(m1[1][i], m2[1][i], k1_);                               \
            m1[1][i] = min(m1[1][i], k1_);                                           \
        }                                                                            \
    } while (0)

#define READB(DST, SLOT)                                                             \
    do {                                                                             \
        const unsigned char* sb_ = ring + (SLOT) * 4096 + (lane << 4);               \
        _Pragma("unroll")                                                            \
        for (int st = 0; st < 4; ++st) DST[st] = *(const f16x8*)(sb_ + st*1024);     \
    } while (0)

    for (int l = 0; l < LEV; ++l) {
        __syncthreads();   // prior level's eeS users done
        ((float4*)eeS)[tid] = ((const float4*)(eebg + (size_t)l * KCODE))[tid];
        __syncthreads();

        const unsigned char* ft = fbase + ((size_t)l << 18) + (lane << 4);

        // drain stray vmem (phase-2/3 loads/stores of previous level) so vmcnt
        // counts below see ONLY our DMA groups (4 loads per tile).
        WAITV(0);
        // prologue: DMA tiles 0..2 into slots 0..2  -> outstanding {0,1,2} = 12
        #pragma unroll
        for (int p = 0; p < 3; ++p) dma_tile(ft + p*4096, ring + p*4096);
        WAITV(8);          // tile 0 complete
        f16x8 Ba[4], Bb[4];
        READB(Ba, 0);
        float eeq_a = eeS[col], eeq_b;

        unsigned m1[2][4], m2[2][4];
        #pragma unroll
        for (int mt = 0; mt < 2; ++mt)
            #pragma unroll
            for (int i = 0; i < 4; ++i) { m1[mt][i] = 0xFFFFFFFFu; m2[mt][i] = 0xFFFFFFFFu; }

        // steady-state invariant entering iter t: outstanding DMAs = {t+1, t+2} (8)
        for (int t = 0; t < NTILES; t += 2) {
            if (t + 3 < NTILES) {
                dma_tile(ft + (size_t)(t+3)*4096, ring + ((t+3)&3)*4096);  // -> {t+1,t+2,t+3}=12
                WAITV(8);                                                   // tile t+1 done
            } else {
                WAITV(0);            // t==62: outstanding {63}; drain -> tile 63 done
            }
            READB(Bb, (t+1)&3);
            eeq_b = eeS[(t+1)*16 + col];
            TILE_COMPUTE(Ba, eeq_a, t);
            if (t + 4 < NTILES) {
                dma_tile(ft + (size_t)(t+4)*4096, ring + ((t+4)&3)*4096);  // -> {t+2,t+3,t+4}=12
                WAITV(8);                                                   // tile t+2 done
                READB(Ba, (t+2)&3);
                eeq_a = eeS[(t+2)*16 + col];
            } else if (t + 2 < NTILES) {
                WAITV(4);            // t==60: outstanding {62,63}; ensure 62 done
                READB(Ba, (t+2)&3);
                eeq_a = eeS[(t+2)*16 + col];
            }
            TILE_COMPUTE(Bb, eeq_b, t + 1);
        }

        // ---- phase 2: cross-lane top-2 reduce (with lane-col meta), select, rescore, update ----
        unsigned k1[2][4], k2[2][4], q1[2][4], q2[2][4];
        #pragma unroll
        for (int mt = 0; mt < 2; ++mt)
            #pragma unroll
            for (int i = 0; i < 4; ++i) {
                k1[mt][i] = m1[mt][i]; k2[mt][i] = m2[mt][i];
                q1[mt][i] = (unsigned)col; q2[mt][i] = (unsigned)col;
            }
        #pragma unroll
        for (int d = 1; d <= 8; d <<= 1) {
            #pragma unroll
            for (int mt = 0; mt < 2; ++mt)
                #pragma unroll
                for (int i = 0; i < 4; ++i) {
                    unsigned ok1 = __shfl_xor(k1[mt][i], d), oq1 = __shfl_xor(q1[mt][i], d);
                    unsigned ok2 = __shfl_xor(k2[mt][i], d), oq2 = __shfl_xor(q2[mt][i], d);
                    bool sw = (ok1 < k1[mt][i]) || (ok1 == k1[mt][i] && oq1 < q1[mt][i]);
                    unsigned n1 = sw ? ok1 : k1[mt][i], nq1 = sw ? oq1 : q1[mt][i];
                    unsigned hk = sw ? k1[mt][i] : ok1, hq = sw ? q1[mt][i] : oq1;
                    bool s2 = (ok2 < k2[mt][i]) || (ok2 == k2[mt][i] && oq2 < q2[mt][i]);
                    unsigned p2 = s2 ? ok2 : k2[mt][i], pq = s2 ? oq2 : q2[mt][i];
                    bool s3 = (p2 < hk) || (p2 == hk && pq < hq);
                    k1[mt][i] = n1;              q1[mt][i] = nq1;
                    k2[mt][i] = s3 ? p2 : hk;    q2[mt][i] = s3 ? pq : hq;
                }
        }

        int jsel = (lane >> 2) & 3;
        int S = ((col >> 2) << 4) | ((col & 3) << 2);   // source lane holding token col's keys

        #pragma unroll
        for (int mt = 0; mt < 2; ++mt) {
            unsigned sk1 = sel4(k1[mt], jsel), sq1 = sel4(q1[mt], jsel);
            unsigned sk2 = sel4(k2[mt], jsel), sq2 = sel4(q2[mt], jsel);
            unsigned bk1 = (unsigned)__shfl((int)sk1, S);
            unsigned bq1 = (unsigned)__shfl((int)sq1, S);
            unsigned bk2 = (unsigned)__shfl((int)sk2, S);
            unsigned bq2 = (unsigned)__shfl((int)sq2, S);
            int c1c = (int)(((bk1 & 63u) << 4) | bq1);
            int c2c = (int)(((bk2 & 63u) << 4) | bq2);
            float d1 = __uint_as_float((bk1 >> 6) | 0x44000000u) - 8192.0f;
            float d2 = __uint_as_float((bk2 >> 6) | 0x44000000u) - 8192.0f;
            int bc = c1c;
            if (d2 - d1 < EPS) {   // ambiguous: exact fp64 rescore of both (uniform per token group)
                double s1 = 0.0, s2d = 0.0;
                const float4* e1 = (const float4*)(cb + ((size_t)l*KCODE + c1c)*DIMV);
                const float4* e2 = (const float4*)(cb + ((size_t)l*KCODE + c2c)*DIMV);
                #pragma unroll
                for (int st = 0; st < 4; ++st) {
                    float4 a = e1[st*8 + q*2], b = e1[st*8 + q*2 + 1];
                    s1 = fma((double)a.x,(double)r[mt][st][0],s1); s1 = fma((double)a.y,(double)r[mt][st][1],s1);
                    s1 = fma((double)a.z,(double)r[mt][st][2],s1); s1 = fma((double)a.w,(double)r[mt][st][3],s1);
                    s1 = fma((double)b.x,(double)r[mt][st][4],s1); s1 = fma((double)b.y,(double)r[mt][st][5],s1);
                    s1 = fma((double)b.z,(double)r[mt][st][6],s1); s1 = fma((double)b.w,(double)r[mt][st][7],s1);
                    float4 a2 = e2[st*8 + q*2], b2 = e2[st*8 + q*2 + 1];
                    s2d = fma((double)a2.x,(double)r[mt][st][0],s2d); s2d = fma((double)a2.y,(double)r[mt][st][1],s2d);
                    s2d = fma((double)a2.z,(double)r[mt][st][2],s2d); s2d = fma((double)a2.w,(double)r[mt][st][3],s2d);
                    s2d = fma((double)b2.x,(double)r[mt][st][4],s2d); s2d = fma((double)b2.y,(double)r[mt][st][5],s2d);
                    s2d = fma((double)b2.z,(double)r[mt][st][6],s2d); s2d = fma((double)b2.w,(double)r[mt][st][7],s2d);
                }
                s1  += __shfl_xor(s1, 16);  s1  += __shfl_xor(s1, 32);
                s2d += __shfl_xor(s2d, 16); s2d += __shfl_xor(s2d, 32);
                double dd1 = ee64g[l*KCODE + c1c] - 2.0*s1;
                double dd2 = ee64g[l*KCODE + c2c] - 2.0*s2d;
                if (dd2 < dd1 || (dd2 == dd1 && c2c < c1c)) bc = c2c;
            }
            // residual update: reference-exact fp32 op chain
            const float4* eb = (const float4*)(cb + ((size_t)l*KCODE + bc)*DIMV);
            #pragma unroll
            for (int st = 0; st < 4; ++st) {
                float4 a = eb[st*8 + q*2], b = eb[st*8 + q*2 + 1];
                float qv[8] = {a.x,a.y,a.z,a.w,b.x,b.y,b.z,b.w};
                #pragma unroll
                for (int j = 0; j < 8; ++j) {
                    float rv = r[mt][st][j];
                    float t1 = qv[j] - rv;              // z_q - residual
                    loss += (double)t1 * (double)t1;
                    float zqst = rv + t1;               // straight-through
                    r[mt][st][j] = rv - zqst;
                }
            }
            if (l < LEV - 1) {   // rebuild A-frags (scaled by -2) for next level
                #pragma unroll
                for (int st = 0; st < 4; ++st) {
                    f16x8 h, lo;
                    #pragma unroll
                    for (int j = 0; j < 8; ++j) {
                        float y = -2.0f * r[mt][st][j];
                        _Float16 hh = (_Float16)y;
                        h[j] = hh;
                        lo[j] = (_Float16)(y - (float)hh);
                    }
                    Ah[mt][st] = h; Al[mt][st] = lo;
                }
            } else {             // final output: z_q_total = z_e - residual_final
                const float4* zp = (const float4*)(ze + (size_t)(tokbase + mt*16 + col)*DIMV);
                float4* op = (float4*)(out + (size_t)(tokbase + mt*16 + col)*DIMV);
                #pragma unroll
                for (int st = 0; st < 4; ++st) {
                    float4 za = zp[st*8 + q*2], zb = zp[st*8 + q*2 + 1];
                    float4 oa, ob;
                    oa.x = za.x - r[mt][st][0]; oa.y = za.y - r[mt][st][1];
                    oa.z = za.z - r[mt][st][2]; oa.w = za.w - r[mt][st][3];
                    ob.x = zb.x - r[mt][st][4]; ob.y = zb.y - r[mt][st][5];
                    ob.z = zb.z - r[mt][st][6]; ob.w = zb.w - r[mt][st][7];
                    op[st*8 + q*2] = oa; op[st*8 + q*2 + 1] = ob;
                }
            }
            if (q == 0) out_idx[(size_t)(tokbase + mt*16 + col)*3 + l] = (float)bc;
        }
    }

    #pragma unroll
    for (int d = 1; d <= 32; d <<= 1) loss += __shfl_xor(loss, d);
    if ((tid & 63) == 0) ssum[wid] = loss;
    __syncthreads();
    if (tid == 0) atomicAdd(ws, ssum[0] + ssum[1] + ssum[2] + ssum[3]);
}

__global__ void rvq_fin(const double* __restrict__ ws, float* __restrict__ out) {
    double vq = ws[0] / ((double)N_TOK * (double)DIMV * (double)LEV);
    out[(size_t)N_TOK * DIMV + 0] = (float)vq;
    out[(size_t)N_TOK * DIMV + 1] = (float)(0.25 * vq);
}

extern "C" void kernel_launch(void* const* d_in, const int* in_sizes, int n_in,
                              void* d_out, int out_size, void* d_ws, size_t ws_size,
                              hipStream_t stream) {
    const float* ze = (const float*)d_in[0];
    const float* cb = (const float*)d_in[1];
    float* out = (float*)d_out;
    double* ws = (double*)d_ws;

    rvq_prep<<<(LEV * KCODE + 255) / 256, 256, 0, stream>>>(cb, ws);
    rvq_main<<<N_TOK / 128, BLOCK, 0, stream>>>(ze, cb, out, ws);
    rvq_fin<<<1, 1, 0, stream>>>(ws, out);
}